// Round 1
// baseline (757.484 us; speedup 1.0000x reference)
//
#include <hip/hip_runtime.h>
#include <hip/hip_bf16.h>
#include <stdint.h>

typedef __hip_bfloat16 bf16;
typedef __bf16 bf16x8 __attribute__((ext_vector_type(8)));
typedef float f32x4 __attribute__((ext_vector_type(4)));

#define DM   1024
#define LSEQ 2048
#define NH   16
#define DH   64
#define BB   2
#define HID  4096
#define MROWS (BB*LSEQ)   // 4096

__device__ __forceinline__ void load_lds16(const void* g, void* l) {
    __builtin_amdgcn_global_load_lds(
        (const __attribute__((address_space(1))) unsigned int*)g,
        (__attribute__((address_space(3))) unsigned int*)l, 16, 0, 0);
}

// ---------------- transpose + cast fp32 [R,C] -> bf16 [C,R] ----------------
__global__ void transpose_cast_f32_bf16(const float* __restrict__ src,
                                        bf16* __restrict__ dst, int R, int C) {
    __shared__ float tile[32][33];
    const int c0 = blockIdx.x * 32, r0 = blockIdx.y * 32;
    const int tx = threadIdx.x & 31, ty = threadIdx.x >> 5; // ty 0..7
#pragma unroll
    for (int i = 0; i < 32; i += 8)
        tile[ty + i][tx] = src[(size_t)(r0 + ty + i) * C + c0 + tx];
    __syncthreads();
#pragma unroll
    for (int i = 0; i < 32; i += 8)
        dst[(size_t)(c0 + ty + i) * R + r0 + tx] = __float2bfloat16(tile[tx][ty + i]);
}

// ---------------- batched bf16 transpose [R,C] -> [C,R] per z ----------------
__global__ void transpose_bf16_batched(const bf16* __restrict__ src,
                                       bf16* __restrict__ dst, int R, int C) {
    const size_t zoff = (size_t)blockIdx.z * R * C;
    src += zoff; dst += zoff;
    __shared__ bf16 tile[32][33];
    const int c0 = blockIdx.x * 32, r0 = blockIdx.y * 32;
    const int tx = threadIdx.x & 31, ty = threadIdx.x >> 5;
#pragma unroll
    for (int i = 0; i < 32; i += 8)
        tile[ty + i][tx] = src[(size_t)(r0 + ty + i) * C + c0 + tx];
    __syncthreads();
#pragma unroll
    for (int i = 0; i < 32; i += 8)
        dst[(size_t)(c0 + ty + i) * R + r0 + tx] = tile[tx][ty + i];
}

// ---------------- RMSNorm + cast to bf16 (one block per row, D=1024) -------
__global__ __launch_bounds__(256)
void rmsnorm_cast(const float* __restrict__ x, const float* __restrict__ scale,
                  bf16* __restrict__ out) {
    const int row = blockIdx.x;
    const int tid = threadIdx.x;
    const float4 v = ((const float4*)(x + (size_t)row * DM))[tid];
    float ss = v.x * v.x + v.y * v.y + v.z * v.z + v.w * v.w;
#pragma unroll
    for (int off = 32; off >= 1; off >>= 1) ss += __shfl_xor(ss, off);
    __shared__ float part[4];
    if ((tid & 63) == 0) part[tid >> 6] = ss;
    __syncthreads();
    const float tot = part[0] + part[1] + part[2] + part[3];
    const float rs = rsqrtf(tot * (1.0f / DM) + 1e-8f);
    const float4 s = ((const float4*)scale)[tid];
    union { bf16 h[4]; uint2 u; } pk;
    pk.h[0] = __float2bfloat16(v.x * rs * s.x);
    pk.h[1] = __float2bfloat16(v.y * rs * s.y);
    pk.h[2] = __float2bfloat16(v.z * rs * s.z);
    pk.h[3] = __float2bfloat16(v.w * rs * s.w);
    ((uint2*)(out + (size_t)row * DM))[tid] = pk.u;
}

// ---------------- generic bf16 GEMM: C[M,N] = A[M,K] @ Bt[N,K]^T ------------
// 128x128 tile, BK=32, 256 thr (4 waves, 2x2), mfma_f32_16x16x32_bf16
template <typename Epi>
__global__ __launch_bounds__(256, 2)
void gemm_bt(const bf16* __restrict__ A, const bf16* __restrict__ Bt,
             int M, int N, int K, Epi epi) {
    __shared__ __align__(16) bf16 sA[128 * 32];
    __shared__ __align__(16) bf16 sB[128 * 32];
    const int tid = threadIdx.x;
    const int wave = tid >> 6, lane = tid & 63;
    const int lo = lane & 15, hi = lane >> 4;
    const int wm = wave & 1, wn = wave >> 1;
    const int m0 = blockIdx.x * 128, n0 = blockIdx.y * 128;
    const int rowA = lane >> 2, cc = (lane & 3) * 8;

    f32x4 acc[4][4];
#pragma unroll
    for (int i = 0; i < 4; i++)
#pragma unroll
        for (int j = 0; j < 4; j++) acc[i][j] = (f32x4){0.f, 0.f, 0.f, 0.f};

    const int nk = K >> 5;
    for (int kt = 0; kt < nk; ++kt) {
        const int k0 = kt * 32;
#pragma unroll
        for (int i = 0; i < 2; ++i) {
            const int slot = wave * 2 + i;
            load_lds16(A + (size_t)(m0 + slot * 16 + rowA) * K + k0 + cc, &sA[slot * 512]);
            load_lds16(Bt + (size_t)(n0 + slot * 16 + rowA) * K + k0 + cc, &sB[slot * 512]);
        }
        __syncthreads();
        bf16x8 a[4], b[4];
#pragma unroll
        for (int i = 0; i < 4; i++)
            a[i] = *(const bf16x8*)&sA[(wm * 64 + i * 16 + lo) * 32 + hi * 8];
#pragma unroll
        for (int j = 0; j < 4; j++)
            b[j] = *(const bf16x8*)&sB[(wn * 64 + j * 16 + lo) * 32 + hi * 8];
#pragma unroll
        for (int i = 0; i < 4; i++)
#pragma unroll
            for (int j = 0; j < 4; j++)
                acc[i][j] = __builtin_amdgcn_mfma_f32_16x16x32_bf16(a[i], b[j], acc[i][j], 0, 0, 0);
        __syncthreads();
    }
#pragma unroll
    for (int i = 0; i < 4; i++) {
        const int row = m0 + wm * 64 + i * 16 + hi * 4;
#pragma unroll
        for (int j = 0; j < 4; j++) {
            const int col = n0 + wn * 64 + j * 16 + lo;
#pragma unroll
            for (int r = 0; r < 4; r++) epi(row + r, col, acc[i][j][r]);
        }
    }
}

// Epilogues
struct EpiQKV {   // scatter into q/k/v [B,H,L,Dh] bf16, + bias
    const float* bias; bf16* q; bf16* k; bf16* v;
    __device__ void operator()(int row, int col, float val) const {
        const float r = val + bias[col];
        const int which = col >> 10, rem = col & 1023;
        const int h = rem >> 6, d = rem & 63;
        const int b = row >> 11, l = row & 2047;
        bf16* dst = which == 0 ? q : (which == 1 ? k : v);
        dst[(((size_t)(b * NH + h)) * LSEQ + l) * DH + d] = __float2bfloat16(r);
    }
};
struct EpiBiasResidF32 {  // out fp32 = val + bias[col] + res[row,col]
    const float* bias; const float* res; float* out; int ldc;
    __device__ void operator()(int row, int col, float val) const {
        const size_t idx = (size_t)row * ldc + col;
        out[idx] = val + bias[col] + res[idx];
    }
};
struct EpiBiasBF16 {      // out bf16 = val + bias[col]
    const float* bias; bf16* out; int ldc;
    __device__ void operator()(int row, int col, float val) const {
        out[(size_t)row * ldc + col] = __float2bfloat16(val + bias[col]);
    }
};

// ---------------- flash attention with analytic ALiBi + causal mask --------
// Q,K: [BH, L, 64] bf16 ; Vt: [BH, 64, L] bf16 ; O: [B, L, 1024] bf16
__global__ __launch_bounds__(256, 2)
void attn_flash(const bf16* __restrict__ Q, const bf16* __restrict__ Kg,
                const bf16* __restrict__ Vt, bf16* __restrict__ O) {
    const int bh = blockIdx.x, qt = blockIdx.y;
    const int b = bh >> 4, h = bh & 15;
    const int tid = threadIdx.x, wave = tid >> 6, lane = tid & 63;
    const int lo = lane & 15, hi = lane >> 4;
    __shared__ __align__(16) bf16 sQ[64 * 64];
    __shared__ __align__(16) bf16 sK[64 * 64];
    __shared__ __align__(16) bf16 sV[64 * 64];
    __shared__ __align__(16) bf16 sP[4][16 * 64];

    const float slope = exp2f(-0.5f * (float)(h + 1));
    const float LOG2E = 1.44269504088896340736f;
    const int q0 = qt * 64;
    const bf16* Qb = Q + (size_t)bh * LSEQ * DH;
    const bf16* Kb = Kg + (size_t)bh * LSEQ * DH;
    const bf16* Vb = Vt + (size_t)bh * DH * LSEQ;

#pragma unroll
    for (int i = 0; i < 2; ++i) {
        const int s = wave * 2 + i;
        load_lds16(Qb + (size_t)(q0 + s * 8 + (lane >> 3)) * DH + (lane & 7) * 8, &sQ[s * 512]);
    }
    __syncthreads();
    bf16x8 aq0 = *(const bf16x8*)&sQ[(wave * 16 + lo) * 64 + hi * 8];
    bf16x8 aq1 = *(const bf16x8*)&sQ[(wave * 16 + lo) * 64 + 32 + hi * 8];

    f32x4 accO[4];
#pragma unroll
    for (int j = 0; j < 4; j++) accO[j] = (f32x4){0.f, 0.f, 0.f, 0.f};
    float mrun[4], lrun[4];
#pragma unroll
    for (int r = 0; r < 4; r++) { mrun[r] = -3.0e30f; lrun[r] = 0.f; }
    const int irow0 = q0 + wave * 16 + hi * 4;

    for (int kt = 0; kt <= qt; ++kt) {
        __syncthreads();   // prev compute done before overwriting sK/sV
#pragma unroll
        for (int i = 0; i < 2; ++i) {
            const int s = wave * 2 + i;
            load_lds16(Kb + (size_t)(kt * 64 + s * 8 + (lane >> 3)) * DH + (lane & 7) * 8, &sK[s * 512]);
            load_lds16(Vb + (size_t)(s * 8 + (lane >> 3)) * LSEQ + kt * 64 + (lane & 7) * 8, &sV[s * 512]);
        }
        __syncthreads();   // staging visible (drains vmcnt)

        f32x4 s4[4];
#pragma unroll
        for (int j = 0; j < 4; j++) {
            bf16x8 bk0 = *(const bf16x8*)&sK[(j * 16 + lo) * 64 + hi * 8];
            bf16x8 bk1 = *(const bf16x8*)&sK[(j * 16 + lo) * 64 + 32 + hi * 8];
            f32x4 z = (f32x4){0.f, 0.f, 0.f, 0.f};
            z = __builtin_amdgcn_mfma_f32_16x16x32_bf16(aq0, bk0, z, 0, 0, 0);
            z = __builtin_amdgcn_mfma_f32_16x16x32_bf16(aq1, bk1, z, 0, 0, 0);
            s4[j] = z;
        }
        float p[4][4], mx[4];
#pragma unroll
        for (int r = 0; r < 4; r++) mx[r] = -3.0e30f;
#pragma unroll
        for (int j = 0; j < 4; j++) {
            const int jg = kt * 64 + j * 16 + lo;
#pragma unroll
            for (int r = 0; r < 4; r++) {
                const int ig = irow0 + r;
                float val = (jg > ig) ? -3.0e30f
                          : (s4[j][r] * 0.125f - slope * (float)(ig - jg)) * LOG2E;
                p[j][r] = val;
                mx[r] = fmaxf(mx[r], val);
            }
        }
#pragma unroll
        for (int off = 8; off >= 1; off >>= 1)
#pragma unroll
            for (int r = 0; r < 4; r++) mx[r] = fmaxf(mx[r], __shfl_xor(mx[r], off));
        float alpha[4], rssum[4];
#pragma unroll
        for (int r = 0; r < 4; r++) {
            const float mnew = fmaxf(mrun[r], mx[r]);
            alpha[r] = exp2f(mrun[r] - mnew);
            mrun[r] = mnew;
            rssum[r] = 0.f;
        }
#pragma unroll
        for (int j = 0; j < 4; j++)
#pragma unroll
            for (int r = 0; r < 4; r++) {
                const float pv = exp2f(p[j][r] - mrun[r]);
                p[j][r] = pv;
                rssum[r] += pv;
            }
#pragma unroll
        for (int off = 8; off >= 1; off >>= 1)
#pragma unroll
            for (int r = 0; r < 4; r++) rssum[r] += __shfl_xor(rssum[r], off);
#pragma unroll
        for (int r = 0; r < 4; r++) lrun[r] = lrun[r] * alpha[r] + rssum[r];
#pragma unroll
        for (int j = 0; j < 4; j++)
#pragma unroll
            for (int r = 0; r < 4; r++) accO[j][r] *= alpha[r];
        // P: C-layout -> A-layout via per-wave LDS round-trip
#pragma unroll
        for (int j = 0; j < 4; j++)
#pragma unroll
            for (int r = 0; r < 4; r++)
                sP[wave][(hi * 4 + r) * 64 + j * 16 + lo] = __float2bfloat16(p[j][r]);
        bf16x8 ap0 = *(const bf16x8*)&sP[wave][lo * 64 + hi * 8];
        bf16x8 ap1 = *(const bf16x8*)&sP[wave][lo * 64 + 32 + hi * 8];
#pragma unroll
        for (int j = 0; j < 4; j++) {
            bf16x8 bv0 = *(const bf16x8*)&sV[(j * 16 + lo) * 64 + hi * 8];
            bf16x8 bv1 = *(const bf16x8*)&sV[(j * 16 + lo) * 64 + 32 + hi * 8];
            accO[j] = __builtin_amdgcn_mfma_f32_16x16x32_bf16(ap0, bv0, accO[j], 0, 0, 0);
            accO[j] = __builtin_amdgcn_mfma_f32_16x16x32_bf16(ap1, bv1, accO[j], 0, 0, 0);
        }
    }
    bf16* Ob = O + (size_t)b * LSEQ * DM + (size_t)h * DH;
#pragma unroll
    for (int r = 0; r < 4; r++) {
        const float inv = 1.0f / lrun[r];
        const int row = q0 + wave * 16 + hi * 4 + r;
#pragma unroll
        for (int j = 0; j < 4; j++)
            Ob[(size_t)row * DM + j * 16 + lo] = __float2bfloat16(accO[j][r] * inv);
    }
}

// ---------------- SwiGLU: ffn_in = silu(h[:,4096:]) * h[:,:4096] -----------
__global__ __launch_bounds__(256)
void swiglu_kernel(const bf16* __restrict__ h, bf16* __restrict__ out) {
    const size_t e = ((size_t)blockIdx.x * 256 + threadIdx.x) * 8; // over 16M
    const int r = (int)(e >> 12), c = (int)(e & 4095);
    const bf16x8 xv = *(const bf16x8*)(h + (size_t)r * (2 * HID) + c);
    const bf16x8 gv = *(const bf16x8*)(h + (size_t)r * (2 * HID) + HID + c);
    bf16x8 o;
#pragma unroll
    for (int t = 0; t < 8; t++) {
        const float g = (float)gv[t];
        const float s = g / (1.f + __expf(-g));
        o[t] = (__bf16)(s * (float)xv[t]);
    }
    *(bf16x8*)(out + (size_t)r * HID + c) = o;
}

// ---------------- launch -----------------------------------------------------
extern "C" void kernel_launch(void* const* d_in, const int* in_sizes, int n_in,
                              void* d_out, int out_size, void* d_ws, size_t ws_size,
                              hipStream_t stream) {
    const float* x      = (const float*)d_in[0];
    const float* w_qkv  = (const float*)d_in[3];
    const float* b_qkv  = (const float*)d_in[4];
    const float* w_o    = (const float*)d_in[5];
    const float* b_o    = (const float*)d_in[6];
    const float* scale1 = (const float*)d_in[7];
    const float* scale2 = (const float*)d_in[8];
    const float* w1     = (const float*)d_in[9];
    const float* b1     = (const float*)d_in[10];
    const float* w2     = (const float*)d_in[11];
    const float* b2     = (const float*)d_in[12];
    float* out = (float*)d_out;

    uint8_t* w = (uint8_t*)d_ws;
    size_t off = 0;
    auto take = [&](size_t bytes) { void* p = w + off; off += (bytes + 255) & ~(size_t)255; return p; };
    bf16* xn    = (bf16*)take((size_t)MROWS * DM * 2);
    bf16* wqkvT = (bf16*)take((size_t)3 * DM * DM * 2);
    bf16* woT   = (bf16*)take((size_t)DM * DM * 2);
    bf16* w1T   = (bf16*)take((size_t)2 * HID * DM * 2);
    bf16* w2T   = (bf16*)take((size_t)DM * HID * 2);
    bf16* qb    = (bf16*)take((size_t)MROWS * DM * 2);
    bf16* kb    = (bf16*)take((size_t)MROWS * DM * 2);
    bf16* vb    = (bf16*)take((size_t)MROWS * DM * 2);
    bf16* vt    = (bf16*)take((size_t)MROWS * DM * 2);
    bf16* ao    = (bf16*)take((size_t)MROWS * DM * 2);
    float* x1   = (float*)take((size_t)MROWS * DM * 4);
    bf16* xn2   = (bf16*)take((size_t)MROWS * DM * 2);
    bf16* hbuf  = (bf16*)take((size_t)MROWS * 2 * HID * 2);
    bf16* ffn   = (bf16*)take((size_t)MROWS * HID * 2);

    // weights -> bf16 transposed [N,K]
    transpose_cast_f32_bf16<<<dim3(3 * DM / 32, DM / 32), 256, 0, stream>>>(w_qkv, wqkvT, DM, 3 * DM);
    transpose_cast_f32_bf16<<<dim3(DM / 32, DM / 32), 256, 0, stream>>>(w_o, woT, DM, DM);
    transpose_cast_f32_bf16<<<dim3(2 * HID / 32, DM / 32), 256, 0, stream>>>(w1, w1T, DM, 2 * HID);
    transpose_cast_f32_bf16<<<dim3(DM / 32, HID / 32), 256, 0, stream>>>(w2, w2T, HID, DM);

    // xn = rmsnorm(x, scale1)
    rmsnorm_cast<<<MROWS, 256, 0, stream>>>(x, scale1, xn);

    // qkv projection -> q,k,v [BH,L,64]
    EpiQKV e1{b_qkv, qb, kb, vb};
    gemm_bt<EpiQKV><<<dim3(MROWS / 128, 3 * DM / 128), 256, 0, stream>>>(xn, wqkvT, MROWS, 3 * DM, DM, e1);

    // v -> vt [BH,64,L]
    transpose_bf16_batched<<<dim3(DH / 32, LSEQ / 32, BB * NH), 256, 0, stream>>>(vb, vt, LSEQ, DH);

    // attention
    attn_flash<<<dim3(BB * NH, LSEQ / 64), 256, 0, stream>>>(qb, kb, vt, ao);

    // o-proj + residual -> x1 (fp32)
    EpiBiasResidF32 e2{b_o, x, x1, DM};
    gemm_bt<EpiBiasResidF32><<<dim3(MROWS / 128, DM / 128), 256, 0, stream>>>(ao, woT, MROWS, DM, DM, e2);

    // xn2 = rmsnorm(x1, scale2)
    rmsnorm_cast<<<MROWS, 256, 0, stream>>>(x1, scale2, xn2);

    // FFN1 -> h [4096, 8192] bf16 (+b1)
    EpiBiasBF16 e3{b1, hbuf, 2 * HID};
    gemm_bt<EpiBiasBF16><<<dim3(MROWS / 128, 2 * HID / 128), 256, 0, stream>>>(xn2, w1T, MROWS, 2 * HID, DM, e3);

    // swiglu -> ffn [4096, 4096] bf16
    swiglu_kernel<<<(int)(((size_t)MROWS * HID / 8) / 256), 256, 0, stream>>>(hbuf, ffn);

    // FFN2 + residual -> out (fp32)
    EpiBiasResidF32 e4{b2, x1, out, DM};
    gemm_bt<EpiBiasResidF32><<<dim3(MROWS / 128, DM / 128), 256, 0, stream>>>(ffn, w2T, MROWS, DM, HID, e4);
}

// Round 2
// 742.190 us; speedup vs baseline: 1.0206x; 1.0206x over previous
//
#include <hip/hip_runtime.h>
#include <hip/hip_bf16.h>
#include <stdint.h>

typedef __hip_bfloat16 bf16;
typedef __bf16 bf16x8 __attribute__((ext_vector_type(8)));
typedef float f32x4 __attribute__((ext_vector_type(4)));

#define DM   1024
#define LSEQ 2048
#define NH   16
#define DH   64
#define BB   2
#define HID  4096
#define MROWS (BB*LSEQ)   // 4096
#define QLD  (3*DM)       // qkv buffer row stride

__device__ __forceinline__ void load_lds16(const void* g, void* l) {
    __builtin_amdgcn_global_load_lds(
        (const __attribute__((address_space(1))) unsigned int*)g,
        (__attribute__((address_space(3))) unsigned int*)l, 16, 0, 0);
}

// ------------- all 4 weight transposes (fp32 [R,C] -> bf16 [C,R]) in one ----
// w1 uses interleaved dest rows: feature f -> row 2f (x_proj), 2f+1 (gate)
__global__ __launch_bounds__(256)
void transpose_all(const float* __restrict__ wqkv, const float* __restrict__ wo,
                   const float* __restrict__ w1, const float* __restrict__ w2,
                   bf16* __restrict__ wqkvT, bf16* __restrict__ woT,
                   bf16* __restrict__ w1T, bf16* __restrict__ w2T) {
    int bid = blockIdx.x;
    const float* src; bf16* dst; int R, C, bx, by; bool inter = false;
    if (bid < 3072)       { src = wqkv; dst = wqkvT; R = 1024; C = 3072; bx = bid % 96;  by = bid / 96; }
    else if (bid < 4096)  { bid -= 3072;  src = wo; dst = woT;  R = 1024; C = 1024; bx = bid % 32;  by = bid / 32; }
    else if (bid < 12288) { bid -= 4096;  src = w1; dst = w1T;  R = 1024; C = 8192; bx = bid % 256; by = bid / 256; inter = true; }
    else                  { bid -= 12288; src = w2; dst = w2T;  R = 4096; C = 1024; bx = bid % 32;  by = bid / 32; }
    __shared__ float tile[32][33];
    const int c0 = bx * 32, r0 = by * 32;
    const int tx = threadIdx.x & 31, ty = threadIdx.x >> 5;
#pragma unroll
    for (int i = 0; i < 32; i += 8)
        tile[ty + i][tx] = src[(size_t)(r0 + ty + i) * C + c0 + tx];
    __syncthreads();
#pragma unroll
    for (int i = 0; i < 32; i += 8) {
        const int c = c0 + ty + i;
        const int drow = inter ? ((c < HID) ? 2 * c : 2 * (c - HID) + 1) : c;
        dst[(size_t)drow * R + r0 + tx] = __float2bfloat16(tile[tx][ty + i]);
    }
}

// ------------- V slice of qkv -> vt [BH, DH, L] -----------------------------
__global__ __launch_bounds__(256)
void v_transpose(const bf16* __restrict__ qkv, bf16* __restrict__ vt) {
    const int bh = blockIdx.z, b = bh >> 4, h = bh & 15;
    const int l0 = blockIdx.x * 32, d0 = blockIdx.y * 32;
    __shared__ bf16 tile[32][33];
    const int tx = threadIdx.x & 31, ty = threadIdx.x >> 5;
#pragma unroll
    for (int i = 0; i < 32; i += 8)
        tile[ty + i][tx] = qkv[((size_t)b * LSEQ + l0 + ty + i) * QLD + 2 * DM + h * DH + d0 + tx];
    __syncthreads();
#pragma unroll
    for (int i = 0; i < 32; i += 8)
        vt[((size_t)bh * DH + d0 + ty + i) * LSEQ + l0 + tx] = tile[tx][ty + i];
}

// ------------- RMSNorm + cast to bf16 (one block per row, D=1024) -----------
__global__ __launch_bounds__(256)
void rmsnorm_cast(const float* __restrict__ x, const float* __restrict__ scale,
                  bf16* __restrict__ out) {
    const int row = blockIdx.x;
    const int tid = threadIdx.x;
    const float4 v = ((const float4*)(x + (size_t)row * DM))[tid];
    float ss = v.x * v.x + v.y * v.y + v.z * v.z + v.w * v.w;
#pragma unroll
    for (int off = 32; off >= 1; off >>= 1) ss += __shfl_xor(ss, off);
    __shared__ float part[4];
    if ((tid & 63) == 0) part[tid >> 6] = ss;
    __syncthreads();
    const float tot = part[0] + part[1] + part[2] + part[3];
    const float rs = rsqrtf(tot * (1.0f / DM) + 1e-8f);
    const float4 s = ((const float4*)scale)[tid];
    union { bf16 h[4]; uint2 u; } pk;
    pk.h[0] = __float2bfloat16(v.x * rs * s.x);
    pk.h[1] = __float2bfloat16(v.y * rs * s.y);
    pk.h[2] = __float2bfloat16(v.z * rs * s.z);
    pk.h[3] = __float2bfloat16(v.w * rs * s.w);
    ((uint2*)(out + (size_t)row * DM))[tid] = pk.u;
}

// ------------- generic bf16 GEMM: C[M,N] = A[M,K] @ Bt[N,K]^T ---------------
template <typename Epi>
__global__ __launch_bounds__(256, 2)
void gemm_bt(const bf16* __restrict__ A, const bf16* __restrict__ Bt,
             int M, int N, int K, Epi epi) {
    __shared__ __align__(16) bf16 sA[128 * 32];
    __shared__ __align__(16) bf16 sB[128 * 32];
    const int tid = threadIdx.x;
    const int wave = tid >> 6, lane = tid & 63;
    const int lo = lane & 15, hi = lane >> 4;
    const int wm = wave & 1, wn = wave >> 1;
    const int m0 = blockIdx.x * 128, n0 = blockIdx.y * 128;
    const int rowA = lane >> 2, cc = (lane & 3) * 8;

    f32x4 acc[4][4];
#pragma unroll
    for (int i = 0; i < 4; i++)
#pragma unroll
        for (int j = 0; j < 4; j++) acc[i][j] = (f32x4){0.f, 0.f, 0.f, 0.f};

    const int nk = K >> 5;
    for (int kt = 0; kt < nk; ++kt) {
        const int k0 = kt * 32;
#pragma unroll
        for (int i = 0; i < 2; ++i) {
            const int slot = wave * 2 + i;
            load_lds16(A + (size_t)(m0 + slot * 16 + rowA) * K + k0 + cc, &sA[slot * 512]);
            load_lds16(Bt + (size_t)(n0 + slot * 16 + rowA) * K + k0 + cc, &sB[slot * 512]);
        }
        __syncthreads();
        bf16x8 a[4], b[4];
#pragma unroll
        for (int i = 0; i < 4; i++)
            a[i] = *(const bf16x8*)&sA[(wm * 64 + i * 16 + lo) * 32 + hi * 8];
#pragma unroll
        for (int j = 0; j < 4; j++)
            b[j] = *(const bf16x8*)&sB[(wn * 64 + j * 16 + lo) * 32 + hi * 8];
#pragma unroll
        for (int i = 0; i < 4; i++)
#pragma unroll
            for (int j = 0; j < 4; j++)
                acc[i][j] = __builtin_amdgcn_mfma_f32_16x16x32_bf16(a[i], b[j], acc[i][j], 0, 0, 0);
        __syncthreads();
    }
#pragma unroll
    for (int i = 0; i < 4; i++) {
        const int row = m0 + wm * 64 + i * 16 + hi * 4;
#pragma unroll
        for (int j = 0; j < 4; j++) {
            const int col = n0 + wn * 64 + j * 16 + lo;
#pragma unroll
            for (int r = 0; r < 4; r++) epi(row + r, col, acc[i][j][r]);
        }
    }
}

// Epilogues
struct EpiBiasBF16 {      // out bf16 = val + bias[col]
    const float* bias; bf16* out; int ldc;
    __device__ void operator()(int row, int col, float val) const {
        out[(size_t)row * ldc + col] = __float2bfloat16(val + bias[col]);
    }
};
struct EpiBiasResidF32 {  // out fp32 = val + bias[col] + res[row,col]
    const float* bias; const float* res; float* out; int ldc;
    __device__ void operator()(int row, int col, float val) const {
        const size_t idx = (size_t)row * ldc + col;
        out[idx] = val + bias[col] + res[idx];
    }
};
struct EpiSwiGLU {        // interleaved cols: even=x_proj feature col/2, odd=gate
    const float* b1; bf16* out;
    __device__ void operator()(int row, int col, float val) const {
        const int orig = (col >> 1) + ((col & 1) ? HID : 0);
        const float v = val + b1[orig];
        const float other = __shfl_xor(v, 1);
        // even lane: v = x_proj, other = gate
        const float g = other;
        const float s = g / (1.f + __expf(-g));
        if (!(threadIdx.x & 1))
            out[(size_t)row * HID + (col >> 1)] = __float2bfloat16(s * v);
    }
};

// ------------- flash attention, analytic ALiBi + causal mask ----------------
// Q,K from qkv [B*L, 3072] (strided); Vt: [BH, 64, L]; O: [B*L, 1024] bf16
__global__ __launch_bounds__(256, 2)
void attn_flash(const bf16* __restrict__ qkv, const bf16* __restrict__ Vt,
                bf16* __restrict__ O) {
    const int bh = blockIdx.x, qt = blockIdx.y;
    const int b = bh >> 4, h = bh & 15;
    const int tid = threadIdx.x, wave = tid >> 6, lane = tid & 63;
    const int lo = lane & 15, hi = lane >> 4;
    __shared__ __align__(16) bf16 sQ[64 * 64];
    __shared__ __align__(16) bf16 sK[64 * 64];
    __shared__ __align__(16) bf16 sV[64 * 64];
    __shared__ __align__(16) bf16 sP[4][16 * 64];

    const float slope = exp2f(-0.5f * (float)(h + 1));
    const float LOG2E = 1.44269504088896340736f;
    const int q0 = qt * 64;
    const bf16* Qb = qkv + (size_t)b * LSEQ * QLD + h * DH;           // q slice
    const bf16* Kb = Qb + DM;                                          // k slice
    const bf16* Vb = Vt + (size_t)bh * DH * LSEQ;

#pragma unroll
    for (int i = 0; i < 2; ++i) {
        const int s = wave * 2 + i;
        load_lds16(Qb + (size_t)(q0 + s * 8 + (lane >> 3)) * QLD + (lane & 7) * 8, &sQ[s * 512]);
    }
    __syncthreads();
    bf16x8 aq0 = *(const bf16x8*)&sQ[(wave * 16 + lo) * 64 + hi * 8];
    bf16x8 aq1 = *(const bf16x8*)&sQ[(wave * 16 + lo) * 64 + 32 + hi * 8];

    f32x4 accO[4];
#pragma unroll
    for (int j = 0; j < 4; j++) accO[j] = (f32x4){0.f, 0.f, 0.f, 0.f};
    float mrun[4], lrun[4];
#pragma unroll
    for (int r = 0; r < 4; r++) { mrun[r] = -3.0e30f; lrun[r] = 0.f; }
    const int irow0 = q0 + wave * 16 + hi * 4;

    for (int kt = 0; kt <= qt; ++kt) {
        __syncthreads();
#pragma unroll
        for (int i = 0; i < 2; ++i) {
            const int s = wave * 2 + i;
            load_lds16(Kb + (size_t)(kt * 64 + s * 8 + (lane >> 3)) * QLD + (lane & 7) * 8, &sK[s * 512]);
            load_lds16(Vb + (size_t)(s * 8 + (lane >> 3)) * LSEQ + kt * 64 + (lane & 7) * 8, &sV[s * 512]);
        }
        __syncthreads();

        f32x4 s4[4];
#pragma unroll
        for (int j = 0; j < 4; j++) {
            bf16x8 bk0 = *(const bf16x8*)&sK[(j * 16 + lo) * 64 + hi * 8];
            bf16x8 bk1 = *(const bf16x8*)&sK[(j * 16 + lo) * 64 + 32 + hi * 8];
            f32x4 z = (f32x4){0.f, 0.f, 0.f, 0.f};
            z = __builtin_amdgcn_mfma_f32_16x16x32_bf16(aq0, bk0, z, 0, 0, 0);
            z = __builtin_amdgcn_mfma_f32_16x16x32_bf16(aq1, bk1, z, 0, 0, 0);
            s4[j] = z;
        }
        float p[4][4], mx[4];
#pragma unroll
        for (int r = 0; r < 4; r++) mx[r] = -3.0e30f;
#pragma unroll
        for (int j = 0; j < 4; j++) {
            const int jg = kt * 64 + j * 16 + lo;
#pragma unroll
            for (int r = 0; r < 4; r++) {
                const int ig = irow0 + r;
                float val = (jg > ig) ? -3.0e30f
                          : (s4[j][r] * 0.125f - slope * (float)(ig - jg)) * LOG2E;
                p[j][r] = val;
                mx[r] = fmaxf(mx[r], val);
            }
        }
#pragma unroll
        for (int off = 8; off >= 1; off >>= 1)
#pragma unroll
            for (int r = 0; r < 4; r++) mx[r] = fmaxf(mx[r], __shfl_xor(mx[r], off));
        float alpha[4], rssum[4];
#pragma unroll
        for (int r = 0; r < 4; r++) {
            const float mnew = fmaxf(mrun[r], mx[r]);
            alpha[r] = exp2f(mrun[r] - mnew);
            mrun[r] = mnew;
            rssum[r] = 0.f;
        }
#pragma unroll
        for (int j = 0; j < 4; j++)
#pragma unroll
            for (int r = 0; r < 4; r++) {
                const float pv = exp2f(p[j][r] - mrun[r]);
                p[j][r] = pv;
                rssum[r] += pv;
            }
#pragma unroll
        for (int off = 8; off >= 1; off >>= 1)
#pragma unroll
            for (int r = 0; r < 4; r++) rssum[r] += __shfl_xor(rssum[r], off);
#pragma unroll
        for (int r = 0; r < 4; r++) lrun[r] = lrun[r] * alpha[r] + rssum[r];
#pragma unroll
        for (int j = 0; j < 4; j++)
#pragma unroll
            for (int r = 0; r < 4; r++) accO[j][r] *= alpha[r];
        // P: C-layout -> A-layout via per-wave LDS round-trip
#pragma unroll
        for (int j = 0; j < 4; j++)
#pragma unroll
            for (int r = 0; r < 4; r++)
                sP[wave][(hi * 4 + r) * 64 + j * 16 + lo] = __float2bfloat16(p[j][r]);
        bf16x8 ap0 = *(const bf16x8*)&sP[wave][lo * 64 + hi * 8];
        bf16x8 ap1 = *(const bf16x8*)&sP[wave][lo * 64 + 32 + hi * 8];
#pragma unroll
        for (int j = 0; j < 4; j++) {
            bf16x8 bv0 = *(const bf16x8*)&sV[(j * 16 + lo) * 64 + hi * 8];
            bf16x8 bv1 = *(const bf16x8*)&sV[(j * 16 + lo) * 64 + 32 + hi * 8];
            accO[j] = __builtin_amdgcn_mfma_f32_16x16x32_bf16(ap0, bv0, accO[j], 0, 0, 0);
            accO[j] = __builtin_amdgcn_mfma_f32_16x16x32_bf16(ap1, bv1, accO[j], 0, 0, 0);
        }
    }
    bf16* Ob = O + (size_t)b * LSEQ * DM + (size_t)h * DH;
#pragma unroll
    for (int r = 0; r < 4; r++) {
        const float inv = 1.0f / lrun[r];
        const int row = q0 + wave * 16 + hi * 4 + r;
#pragma unroll
        for (int j = 0; j < 4; j++)
            Ob[(size_t)row * DM + j * 16 + lo] = __float2bfloat16(accO[j][r] * inv);
    }
}

// ---------------- launch ----------------------------------------------------
extern "C" void kernel_launch(void* const* d_in, const int* in_sizes, int n_in,
                              void* d_out, int out_size, void* d_ws, size_t ws_size,
                              hipStream_t stream) {
    const float* x      = (const float*)d_in[0];
    const float* w_qkv  = (const float*)d_in[3];
    const float* b_qkv  = (const float*)d_in[4];
    const float* w_o    = (const float*)d_in[5];
    const float* b_o    = (const float*)d_in[6];
    const float* scale1 = (const float*)d_in[7];
    const float* scale2 = (const float*)d_in[8];
    const float* w1     = (const float*)d_in[9];
    const float* b1     = (const float*)d_in[10];
    const float* w2     = (const float*)d_in[11];
    const float* b2     = (const float*)d_in[12];
    float* out = (float*)d_out;

    uint8_t* w = (uint8_t*)d_ws;
    size_t off = 0;
    auto take = [&](size_t bytes) { void* p = w + off; off += (bytes + 255) & ~(size_t)255; return p; };
    bf16* xn    = (bf16*)take((size_t)MROWS * DM * 2);
    bf16* wqkvT = (bf16*)take((size_t)3 * DM * DM * 2);
    bf16* woT   = (bf16*)take((size_t)DM * DM * 2);
    bf16* w1T   = (bf16*)take((size_t)2 * HID * DM * 2);
    bf16* w2T   = (bf16*)take((size_t)DM * HID * 2);
    bf16* qkvb  = (bf16*)take((size_t)MROWS * QLD * 2);
    bf16* vt    = (bf16*)take((size_t)MROWS * DM * 2);
    bf16* ao    = (bf16*)take((size_t)MROWS * DM * 2);
    float* x1   = (float*)take((size_t)MROWS * DM * 4);
    bf16* xn2   = (bf16*)take((size_t)MROWS * DM * 2);
    bf16* ffn   = (bf16*)take((size_t)MROWS * HID * 2);

    // all weights -> bf16 transposed [N,K] (w1 interleaved), one dispatch
    transpose_all<<<16384, 256, 0, stream>>>(w_qkv, w_o, w1, w2, wqkvT, woT, w1T, w2T);

    // xn = rmsnorm(x, scale1)
    rmsnorm_cast<<<MROWS, 256, 0, stream>>>(x, scale1, xn);

    // qkv projection -> qkvb [M, 3072] bf16
    EpiBiasBF16 e1{b_qkv, qkvb, QLD};
    gemm_bt<EpiBiasBF16><<<dim3(MROWS / 128, QLD / 128), 256, 0, stream>>>(xn, wqkvT, MROWS, QLD, DM, e1);

    // v slice -> vt [BH,64,L]
    v_transpose<<<dim3(LSEQ / 32, DH / 32, BB * NH), 256, 0, stream>>>(qkvb, vt);

    // attention
    attn_flash<<<dim3(BB * NH, LSEQ / 64), 256, 0, stream>>>(qkvb, vt, ao);

    // o-proj + residual -> x1 (fp32)
    EpiBiasResidF32 e2{b_o, x, x1, DM};
    gemm_bt<EpiBiasResidF32><<<dim3(MROWS / 128, DM / 128), 256, 0, stream>>>(ao, woT, MROWS, DM, DM, e2);

    // xn2 = rmsnorm(x1, scale2)
    rmsnorm_cast<<<MROWS, 256, 0, stream>>>(x1, scale2, xn2);

    // FFN1 + fused SwiGLU -> ffn [4096, 4096] bf16
    EpiSwiGLU e3{b1, ffn};
    gemm_bt<EpiSwiGLU><<<dim3(MROWS / 128, 2 * HID / 128), 256, 0, stream>>>(xn2, w1T, MROWS, 2 * HID, DM, e3);

    // FFN2 + residual -> out (fp32)
    EpiBiasResidF32 e4{b2, x1, out, DM};
    gemm_bt<EpiBiasResidF32><<<dim3(MROWS / 128, DM / 128), 256, 0, stream>>>(ffn, w2T, MROWS, DM, HID, e4);
}